// Round 10
// baseline (252.946 us; speedup 1.0000x reference)
//
#include <hip/hip_runtime.h>
#include <hip/hip_bf16.h>

// Problem constants
#define Bc 8
#define Tc 2048
#define Ec 256
#define Hc 2
#define HDc 128
#define Mrows (Bc*Tc)          // 16384
#define M2c 134

using bfx8  = __attribute__((ext_vector_type(8))) __bf16;
using f32x4 = __attribute__((ext_vector_type(4))) float;

__device__ __forceinline__ void gll16(const __bf16* g, __bf16* lds) {
    __builtin_amdgcn_global_load_lds(
        (const __attribute__((address_space(1))) unsigned int*)g,
        (__attribute__((address_space(3))) unsigned int*)lds, 16, 0, 0);
}

// ---------------- embed + relu + LN1, fused weight-conversion + embsum zero ----------------
__global__ __launch_bounds__(256) void embed_prep_k(const float* X, const float* wpe,
                                                    const float* g, const float* bb,
                                                    const float* attn_w, const float* apw,
                                                    const float* fcw, const float* mpw,
                                                    __bf16* wb, float* embsum,
                                                    __bf16* xres, __bf16* hb) {
    int m = blockIdx.x;
    int e = threadIdx.x;
    if (m < 2048) {
        int i = m * 256 + e;
        if (i < 196608)       wb[i] = (__bf16)attn_w[i];
        else if (i < 262144)  wb[i] = (__bf16)apw[i - 196608];
        else if (i < 393216)  wb[i] = (__bf16)fcw[i - 262144];
        else                  wb[i] = (__bf16)mpw[i - 393216];
        if (m < 8) embsum[m * 256 + e] = 0.f;
    }
    int t = m & (Tc - 1);
    float v = X[(size_t)m * Ec + e] + wpe[(size_t)t * Ec + e] + wpe[(size_t)(t >= 1024) * Ec + e];
    v = fmaxf(v, 0.f);
    xres[(size_t)m * Ec + e] = (__bf16)v;
    float s1 = v, s2 = v * v;
    #pragma unroll
    for (int o = 32; o; o >>= 1) { s1 += __shfl_xor(s1, o, 64); s2 += __shfl_xor(s2, o, 64); }
    __shared__ float a1[4], a2[4];
    int w = threadIdx.x >> 6;
    if ((threadIdx.x & 63) == 0) { a1[w] = s1; a2[w] = s2; }
    __syncthreads();
    float m1 = (a1[0] + a1[1] + a1[2] + a1[3]) * (1.f / 256.f);
    float m2 = (a2[0] + a2[1] + a2[2] + a2[3]) * (1.f / 256.f);
    float r = rsqrtf(m2 - m1 * m1 + 1e-5f);
    hb[(size_t)m * Ec + e] = (__bf16)((v - m1) * r * g[e] + bb[e]);
}

// ---------------- qkv GEMM (128x128 tile) + fused V-transpose ----------------
// Q/K scatter as before; V blocks (n0>=512) transpose their 128t x 128d tile
// through LDS and write Vt[bh][d][t] coalesced. transpose_v kernel deleted.
__global__ __launch_bounds__(256) void gemm_qkv(const __bf16* __restrict__ A,
                                                const __bf16* __restrict__ Bw,
                                                const float* __restrict__ bias,
                                                __bf16* __restrict__ Qb,
                                                __bf16* __restrict__ Kb,
                                                unsigned short* __restrict__ Vt) {
    const int K = 256;
    __shared__ __bf16 As[128 * 64];
    __shared__ __bf16 Bs[128 * 64];
    __shared__ unsigned short trans[128][136];   // 34KB, V-transpose buffer
    const int tid = threadIdx.x, w = tid >> 6, l = tid & 63;
    const int m0 = blockIdx.y * 128, n0 = blockIdx.x * 128;
    const int wr = w >> 1, wc = w & 1;
    const int quad = l >> 4, col15 = l & 15;
    const int isV = (n0 >= 512);

    f32x4 acc[4][4];
    f32x4 zz = {0.f, 0.f, 0.f, 0.f};
    #pragma unroll
    for (int i = 0; i < 4; i++)
        #pragma unroll
        for (int j = 0; j < 4; j++) acc[i][j] = zz;

    const int lrow = l >> 3;
    const int pbs  = l & 7;

    for (int kb = 0; kb < K; kb += 64) {
        #pragma unroll
        for (int it = 0; it < 4; it++) {
            int chunk = w * 4 + it;
            int row = chunk * 8 + lrow;
            int lb = pbs ^ (row & 7);
            gll16(A  + (size_t)(m0 + row) * K + kb + lb * 8, As + chunk * 512);
            gll16(Bw + (size_t)(n0 + row) * K + kb + lb * 8, Bs + chunk * 512);
        }
        __syncthreads();
        #pragma unroll
        for (int ks = 0; ks < 2; ks++) {
            bfx8 af[4], bfr[4];
            #pragma unroll
            for (int rt = 0; rt < 4; rt++) {
                int row = wr * 64 + rt * 16 + col15;
                int pb = (ks * 4 + quad) ^ (row & 7);
                af[rt] = *(const bfx8*)(As + row * 64 + pb * 8);
            }
            #pragma unroll
            for (int ct = 0; ct < 4; ct++) {
                int row = wc * 64 + ct * 16 + col15;
                int pb = (ks * 4 + quad) ^ (row & 7);
                bfr[ct] = *(const bfx8*)(Bs + row * 64 + pb * 8);
            }
            #pragma unroll
            for (int rt = 0; rt < 4; rt++)
                #pragma unroll
                for (int ct = 0; ct < 4; ct++)
                    acc[rt][ct] = __builtin_amdgcn_mfma_f32_16x16x32_bf16(af[rt], bfr[ct], acc[rt][ct], 0, 0, 0);
        }
        __syncthreads();
    }

    #pragma unroll
    for (int rt = 0; rt < 4; rt++)
        #pragma unroll
        for (int ct = 0; ct < 4; ct++) {
            int ng  = n0 + wc * 64 + ct * 16 + col15;
            float bsv = bias[ng];
            #pragma unroll
            for (int r = 0; r < 4; r++) {
                int mg = m0 + wr * 64 + rt * 16 + quad * 4 + r;
                float val = fmaxf(acc[rt][ct][r] + bsv, 0.f);
                __bf16 bv = (__bf16)val;
                if (isV) {
                    int d = ng & 127;
                    int tl = mg - m0;
                    trans[d][tl] = *(unsigned short*)&bv;
                } else {
                    int sel = ng >> 8;            // 0:q 1:k
                    int hh = (ng >> 7) & 1;
                    int d = ng & 127;
                    int bb = mg >> 11, tt = mg & (Tc - 1);
                    size_t idx = ((size_t)((bb * 2 + hh) * Tc + tt)) * HDc + d;
                    if (sel == 0) Qb[idx] = bv;
                    else Kb[idx] = bv;
                }
            }
        }
    if (isV) {
        __syncthreads();
        int h = (n0 >> 7) & 1;
        int b = m0 >> 11, t0 = m0 & (Tc - 1);
        int bh = b * 2 + h;
        int d = tid >> 1, th = tid & 1;
        unsigned short* dst = Vt + ((size_t)(bh * HDc + d)) * Tc + t0 + th * 64;
        const unsigned short* src = &trans[d][th * 64];
        #pragma unroll
        for (int i = 0; i < 8; i++)
            *(uint4*)(dst + i * 8) = *(const uint4*)(src + i * 8);
    }
}

// ---------------- causal relu attention v6 (unchanged) ----------------
__global__ __launch_bounds__(256, 4) void attn6_k(const __bf16* __restrict__ Qb,
                                                  const __bf16* __restrict__ Kb,
                                                  const __bf16* __restrict__ Vt,
                                                  __bf16* __restrict__ Y1,
                                                  __bf16* __restrict__ Y2,
                                                  __bf16* __restrict__ Y3,
                                                  __bf16* __restrict__ Y4) {
    __shared__ __bf16 Ks[64 * 128];   // 16KB
    __shared__ __bf16 Vs[128 * 64];   // 16KB
    __shared__ __bf16 Ss[64 * 64];    // 8KB
    int bid = blockIdx.x;             // 0..1279
    int lane8 = bid & 7;
    int s = bid >> 3;                 // 0..159
    int bh = ((s & 1) << 3) | lane8;
    int f = s >> 1;                   // 0..79
    int qt, ch;
    if (f < 8)       { qt = f;                    ch = 0; }
    else if (f < 24) { qt = 8 + ((f - 8) >> 1);   ch = (f - 8) & 1; }
    else if (f < 48) { int r = f - 24; int d3 = r / 3; qt = 16 + d3; ch = r - 3 * d3; }
    else             { int r = f - 48; qt = 24 + (r >> 2); ch = r & 3; }
    int Q0 = qt * 64;
    int kts = ch * 8;
    int kte = min(kts + 8, qt + 1);

    int tid = threadIdx.x, w = tid >> 6, l = tid & 63;
    int quad = l >> 4, col15 = l & 15;
    const int lrowK = l >> 4, pbsK = l & 15;
    const int lrowV = l >> 3, pbsV = l & 7;

    #pragma unroll
    for (int it = 0; it < 4; it++) {
        int chunk = w * 4 + it;
        int row = chunk * 4 + lrowK;
        int lb = pbsK ^ (row & 7);
        gll16(Qb + ((size_t)(bh * Tc + Q0 + row)) * HDc + lb * 8, Ks + chunk * 512);
    }
    __syncthreads();
    bfx8 qf[4];
    #pragma unroll
    for (int ks = 0; ks < 4; ks++) {
        int row = w * 16 + col15;
        int pb = (ks * 4 + quad) ^ (row & 7);
        qf[ks] = *(const bfx8*)(Ks + row * 128 + pb * 8);
    }

    f32x4 zz = {0.f, 0.f, 0.f, 0.f};
    f32x4 yacc[8];
    #pragma unroll
    for (int i = 0; i < 8; i++) yacc[i] = zz;

    for (int kt = kts; kt < kte; kt++) {
        __syncthreads();
        #pragma unroll
        for (int it = 0; it < 4; it++) {
            int chunk = w * 4 + it;
            int rowK = chunk * 4 + lrowK;
            int lbK = pbsK ^ (rowK & 7);
            gll16(Kb + ((size_t)(bh * Tc + kt * 64 + rowK)) * HDc + lbK * 8, Ks + chunk * 512);
            int rowV = chunk * 8 + lrowV;
            int lbV = pbsV ^ (rowV & 7);
            gll16(Vt + ((size_t)(bh * HDc + rowV)) * Tc + kt * 64 + lbV * 8, Vs + chunk * 512);
        }
        __syncthreads();

        f32x4 sacc[4];
        #pragma unroll
        for (int i = 0; i < 4; i++) sacc[i] = zz;
        #pragma unroll
        for (int ks = 0; ks < 4; ks++) {
            #pragma unroll
            for (int ct = 0; ct < 4; ct++) {
                int row = ct * 16 + col15;
                int pb = (ks * 4 + quad) ^ (row & 7);
                bfx8 kf = *(const bfx8*)(Ks + row * 128 + pb * 8);
                sacc[ct] = __builtin_amdgcn_mfma_f32_16x16x32_bf16(qf[ks], kf, sacc[ct], 0, 0, 0);
            }
        }

        #pragma unroll
        for (int ct = 0; ct < 4; ct++) {
            int kl = ct * 16 + col15;
            int kg = kt * 64 + kl;
            int blk = kl >> 3, off = kl & 7;
            #pragma unroll
            for (int r = 0; r < 4; r++) {
                int qlw = w * 16 + quad * 4 + r;
                float val = (kg <= Q0 + qlw) ? fmaxf(sacc[ct][r], 0.f) : 0.f;
                int pb = blk ^ (qlw & 7);
                Ss[qlw * 64 + pb * 8 + off] = (__bf16)val;
            }
        }

        #pragma unroll
        for (int ks = 0; ks < 2; ks++) {
            int rowS = w * 16 + col15;
            int pbS = (ks * 4 + quad) ^ (rowS & 7);
            bfx8 sf = *(const bfx8*)(Ss + rowS * 64 + pbS * 8);
            #pragma unroll
            for (int dt = 0; dt < 8; dt++) {
                int row = dt * 16 + col15;
                int pb = (ks * 4 + quad) ^ (row & 7);
                bfx8 vf = *(const bfx8*)(Vs + row * 64 + pb * 8);
                yacc[dt] = __builtin_amdgcn_mfma_f32_16x16x32_bf16(sf, vf, yacc[dt], 0, 0, 0);
            }
        }
    }

    __bf16* Yp = (ch == 0) ? Y1 : (ch == 1) ? Y2 : (ch == 2) ? Y3 : Y4;
    int b = bh >> 1, h = bh & 1;
    const float sc = 0.08838834764831845f;  // 1/sqrt(128)
    #pragma unroll
    for (int dt = 0; dt < 8; dt++) {
        int d = dt * 16 + col15;
        #pragma unroll
        for (int r = 0; r < 4; r++) {
            int q = Q0 + w * 16 + quad * 4 + r;
            Yp[((size_t)(b * Tc + q)) * Ec + h * HDc + d] = (__bf16)(yacc[dt][r] * sc);
        }
    }
}

// ---------------- MEGA v2: col-partitioned waves, B from global, barrier-light ----------------
// 32 rows/block, grid 512 (2 blocks/CU). Wave w owns a column slice; A-operands
// (SumY, h2, fc) shared via LDS; B-fragments read directly from global (L2-hot
// weights, one pass per block). Only 6 barriers total; K-loops barrier-free.
__global__ __launch_bounds__(256, 2) void mega_k(const __bf16* __restrict__ Y1,
                                                 const __bf16* __restrict__ Y2,
                                                 const __bf16* __restrict__ Y3,
                                                 const __bf16* __restrict__ Y4,
                                                 const __bf16* __restrict__ wap,
                                                 const float* __restrict__ apbias,
                                                 const __bf16* __restrict__ xres,
                                                 const float* __restrict__ ln2_g,
                                                 const float* __restrict__ ln2_b,
                                                 const __bf16* __restrict__ wfc,
                                                 const float* __restrict__ fcbias,
                                                 const __bf16* __restrict__ wmp,
                                                 const float* __restrict__ mpbias,
                                                 const float* __restrict__ lnf_g,
                                                 const float* __restrict__ lnf_b,
                                                 float* __restrict__ embsum) {
    __shared__ __bf16 fcs[32 * 512];   // 32KB; first 16KB aliased as As during P1
    __shared__ __bf16 h2s[32 * 256];   // 16KB
    __shared__ float red1[32][4], red2[32][4];
    __shared__ float cs[256];
    __bf16* As = fcs;                  // 32x256, dead before fcs is written

    const int tid = threadIdx.x, w = tid >> 6, l = tid & 63;
    const int m0 = blockIdx.x * 32;
    const int quad = l >> 4, col15 = l & 15;
    f32x4 zz = {0.f, 0.f, 0.f, 0.f};

    int qt = (m0 & (Tc - 1)) >> 6;
    int nsum = (qt + 8) >> 3;          // 1..4 Y partials
    const __bf16* Ys[4] = {Y1, Y2, Y3, Y4};

    // ---- stage A = SumY (32 x 256) into As, swizzled ----
    #pragma unroll
    for (int it = 0; it < 4; it++) {
        int idx = it * 256 + tid;
        int row = idx >> 5, blk = idx & 31;
        size_t off = (size_t)(m0 + row) * 256 + blk * 8;
        bfx8 a1 = *(const bfx8*)(Y1 + off);
        float tmp[8];
        #pragma unroll
        for (int jj = 0; jj < 8; jj++) tmp[jj] = (float)a1[jj];
        for (int j = 1; j < nsum; j++) {
            bfx8 aj = *(const bfx8*)(Ys[j] + off);
            #pragma unroll
            for (int jj = 0; jj < 8; jj++) tmp[jj] += (float)aj[jj];
        }
        #pragma unroll
        for (int jj = 0; jj < 8; jj++) a1[jj] = (__bf16)tmp[jj];
        *(bfx8*)(As + row * 256 + (blk ^ (row & 7)) * 8) = a1;
    }
    __syncthreads();

    // ---- P1: attnproj, wave w owns cols w*64..+63 ----
    f32x4 acc1[2][4];
    #pragma unroll
    for (int rt = 0; rt < 2; rt++)
        #pragma unroll
        for (int ct = 0; ct < 4; ct++) acc1[rt][ct] = zz;
    #pragma unroll
    for (int kw = 0; kw < 8; kw++) {
        bfx8 af[2], bf[4];
        #pragma unroll
        for (int rt = 0; rt < 2; rt++) {
            int row = rt * 16 + col15;
            int pb = (kw * 4 + quad) ^ (row & 7);
            af[rt] = *(const bfx8*)(As + row * 256 + pb * 8);
        }
        #pragma unroll
        for (int ct = 0; ct < 4; ct++)
            bf[ct] = *(const bfx8*)(wap + (size_t)(w * 64 + ct * 16 + col15) * 256 + kw * 32 + quad * 8);
        #pragma unroll
        for (int rt = 0; rt < 2; rt++)
            #pragma unroll
            for (int ct = 0; ct < 4; ct++)
                acc1[rt][ct] = __builtin_amdgcn_mfma_f32_16x16x32_bf16(af[rt], bf[ct], acc1[rt][ct], 0, 0, 0);
    }

    // ---- P1 epilogue: x2 = resid + C + bias (VGPR); LN2 -> h2s ----
    float xv[2][4][4];
    #pragma unroll
    for (int rt = 0; rt < 2; rt++)
        #pragma unroll
        for (int ct = 0; ct < 4; ct++) {
            int ng = w * 64 + ct * 16 + col15;
            float bsv = apbias[ng];
            #pragma unroll
            for (int r = 0; r < 4; r++) {
                int mg = m0 + rt * 16 + quad * 4 + r;
                xv[rt][ct][r] = acc1[rt][ct][r] + bsv + (float)xres[(size_t)mg * 256 + ng];
            }
        }
    #pragma unroll
    for (int rt = 0; rt < 2; rt++)
        #pragma unroll
        for (int r = 0; r < 4; r++) {
            float a = 0.f, b2 = 0.f;
            #pragma unroll
            for (int ct = 0; ct < 4; ct++) { a += xv[rt][ct][r]; b2 += xv[rt][ct][r] * xv[rt][ct][r]; }
            #pragma unroll
            for (int o = 1; o < 16; o <<= 1) { a += __shfl_xor(a, o, 64); b2 += __shfl_xor(b2, o, 64); }
            if (col15 == 0) {
                int row = rt * 16 + quad * 4 + r;
                red1[row][w] = a; red2[row][w] = b2;
            }
        }
    __syncthreads();
    #pragma unroll
    for (int rt = 0; rt < 2; rt++)
        #pragma unroll
        for (int r = 0; r < 4; r++) {
            int row = rt * 16 + quad * 4 + r;
            float s1 = red1[row][0] + red1[row][1] + red1[row][2] + red1[row][3];
            float s2 = red2[row][0] + red2[row][1] + red2[row][2] + red2[row][3];
            float mu = s1 * (1.f / 256.f);
            float var = s2 * (1.f / 256.f) - mu * mu;
            float rs = rsqrtf(var + 1e-5f);
            #pragma unroll
            for (int ct = 0; ct < 4; ct++) {
                int ng = w * 64 + ct * 16 + col15;
                float h = (xv[rt][ct][r] - mu) * rs * ln2_g[ng] + ln2_b[ng];
                h2s[row * 256 + ((ng >> 3) ^ (row & 7)) * 8 + (ng & 7)] = (__bf16)h;
            }
        }
    __syncthreads();

    // ---- P2: fc = relu(h2 @ wfc^T + b), wave w owns cols w*128..+127 (2 groups of 64) ----
    for (int g2 = 0; g2 < 2; g2++) {
        f32x4 acc2[2][4];
        #pragma unroll
        for (int rt = 0; rt < 2; rt++)
            #pragma unroll
            for (int ct = 0; ct < 4; ct++) acc2[rt][ct] = zz;
        #pragma unroll
        for (int kw = 0; kw < 8; kw++) {
            bfx8 af[2], bf[4];
            #pragma unroll
            for (int rt = 0; rt < 2; rt++) {
                int row = rt * 16 + col15;
                int pb = (kw * 4 + quad) ^ (row & 7);
                af[rt] = *(const bfx8*)(h2s + row * 256 + pb * 8);
            }
            #pragma unroll
            for (int ct = 0; ct < 4; ct++)
                bf[ct] = *(const bfx8*)(wfc + (size_t)(w * 128 + g2 * 64 + ct * 16 + col15) * 256 + kw * 32 + quad * 8);
            #pragma unroll
            for (int rt = 0; rt < 2; rt++)
                #pragma unroll
                for (int ct = 0; ct < 4; ct++)
                    acc2[rt][ct] = __builtin_amdgcn_mfma_f32_16x16x32_bf16(af[rt], bf[ct], acc2[rt][ct], 0, 0, 0);
        }
        #pragma unroll
        for (int rt = 0; rt < 2; rt++)
            #pragma unroll
            for (int ct = 0; ct < 4; ct++) {
                int col = w * 128 + g2 * 64 + ct * 16 + col15;
                float bsv = fcbias[col];
                #pragma unroll
                for (int r = 0; r < 4; r++) {
                    int row = rt * 16 + quad * 4 + r;
                    float val = fmaxf(acc2[rt][ct][r] + bsv, 0.f);
                    fcs[row * 512 + ((col >> 3) ^ (row & 7)) * 8 + (col & 7)] = (__bf16)val;
                }
            }
    }
    __syncthreads();

    // ---- P3: mlpproj, wave w owns cols w*64..+63, K=512 ----
    f32x4 acc3[2][4];
    #pragma unroll
    for (int rt = 0; rt < 2; rt++)
        #pragma unroll
        for (int ct = 0; ct < 4; ct++) acc3[rt][ct] = zz;
    #pragma unroll
    for (int kw = 0; kw < 16; kw++) {
        bfx8 af[2], bf[4];
        #pragma unroll
        for (int rt = 0; rt < 2; rt++) {
            int row = rt * 16 + col15;
            int pb = (kw * 4 + quad) ^ (row & 7);
            af[rt] = *(const bfx8*)(fcs + row * 512 + pb * 8);
        }
        #pragma unroll
        for (int ct = 0; ct < 4; ct++)
            bf[ct] = *(const bfx8*)(wmp + (size_t)(w * 64 + ct * 16 + col15) * 512 + kw * 32 + quad * 8);
        #pragma unroll
        for (int rt = 0; rt < 2; rt++)
            #pragma unroll
            for (int ct = 0; ct < 4; ct++)
                acc3[rt][ct] = __builtin_amdgcn_mfma_f32_16x16x32_bf16(af[rt], bf[ct], acc3[rt][ct], 0, 0, 0);
    }

    // ---- P4: x3 = relu(x2 + C + b); LNf; colsum of relu(LN) -> embsum ----
    #pragma unroll
    for (int rt = 0; rt < 2; rt++)
        #pragma unroll
        for (int ct = 0; ct < 4; ct++) {
            int ng = w * 64 + ct * 16 + col15;
            float bsv = mpbias[ng];
            #pragma unroll
            for (int r = 0; r < 4; r++)
                xv[rt][ct][r] = fmaxf(acc3[rt][ct][r] + bsv + xv[rt][ct][r], 0.f);
        }
    __syncthreads();   // red1/red2 free for reuse
    #pragma unroll
    for (int rt = 0; rt < 2; rt++)
        #pragma unroll
        for (int r = 0; r < 4; r++) {
            float a = 0.f, b2 = 0.f;
            #pragma unroll
            for (int ct = 0; ct < 4; ct++) { a += xv[rt][ct][r]; b2 += xv[rt][ct][r] * xv[rt][ct][r]; }
            #pragma unroll
            for (int o = 1; o < 16; o <<= 1) { a += __shfl_xor(a, o, 64); b2 += __shfl_xor(b2, o, 64); }
            if (col15 == 0) {
                int row = rt * 16 + quad * 4 + r;
                red1[row][w] = a; red2[row][w] = b2;
            }
        }
    __syncthreads();
    float colsum[4] = {0.f, 0.f, 0.f, 0.f};
    #pragma unroll
    for (int rt = 0; rt < 2; rt++)
        #pragma unroll
        for (int r = 0; r < 4; r++) {
            int row = rt * 16 + quad * 4 + r;
            float s1 = red1[row][0] + red1[row][1] + red1[row][2] + red1[row][3];
            float s2 = red2[row][0] + red2[row][1] + red2[row][2] + red2[row][3];
            float mu = s1 * (1.f / 256.f);
            float var = s2 * (1.f / 256.f) - mu * mu;
            float rs = rsqrtf(var + 1e-5f);
            #pragma unroll
            for (int ct = 0; ct < 4; ct++) {
                int ng = w * 64 + ct * 16 + col15;
                float h = (xv[rt][ct][r] - mu) * rs * lnf_g[ng] + lnf_b[ng];
                colsum[ct] += fmaxf(h, 0.f);
            }
        }
    #pragma unroll
    for (int ct = 0; ct < 4; ct++) {
        colsum[ct] += __shfl_xor(colsum[ct], 16, 64);
        colsum[ct] += __shfl_xor(colsum[ct], 32, 64);
    }
    if (quad == 0) {
        #pragma unroll
        for (int ct = 0; ct < 4; ct++)
            cs[w * 64 + ct * 16 + col15] = colsum[ct];
    }
    __syncthreads();
    atomicAdd(&embsum[(m0 >> 11) * 256 + tid], cs[tid]);
}

// ---------------- final: emb, logits, losses, outputs — FLOAT32 output ----------------
__global__ __launch_bounds__(256) void final_k(const float* embsum, const float* Yt,
                                               const float* head_w, const float* head_b,
                                               float* out) {
    __shared__ float semb[2048];
    __shared__ float slog[1072];
    int tid = threadIdx.x;
    for (int i = tid; i < 2048; i += 256) semb[i] = embsum[i] * (1.f / 2048.f);
    __syncthreads();
    float part1 = 0.f;
    for (int idx = tid; idx < 1072; idx += 256) {
        int b = idx / M2c, n = idx - b * M2c;
        float acc = head_b[n];
        const float* wn = head_w + (size_t)n * Ec;
        const float* e = semb + b * Ec;
        #pragma unroll 8
        for (int k = 0; k < Ec; k++) acc += e[k] * wn[k];
        acc = fmaxf(acc, 0.f);
        slog[idx] = acc;
        float d = acc - Yt[idx];
        part1 += d * d;
    }
    float part3 = 0.f;
    for (int idx = tid; idx < 1024; idx += 256) {
        int b = idx >> 7, i = idx & 127;
        float d = semb[b * Ec + i] - semb[b * Ec + 128 + i];
        part3 += d * d;
    }
    #pragma unroll
    for (int o = 32; o; o >>= 1) { part1 += __shfl_xor(part1, o, 64); part3 += __shfl_xor(part3, o, 64); }
    __shared__ float r1[4], r3[4];
    int w = tid >> 6;
    if ((tid & 63) == 0) { r1[w] = part1; r3[w] = part3; }
    __syncthreads();
    float l1 = sqrtf((r1[0] + r1[1] + r1[2] + r1[3]) / 1072.f);
    float l3 = sqrtf((r3[0] + r3[1] + r3[2] + r3[3]) / 1024.f);
    for (int idx = tid; idx < 1024; idx += 256) {
        int b = idx >> 7, i = idx & 127;
        out[idx]        = semb[b * Ec + i];
        out[1024 + idx] = semb[b * Ec + 128 + i];
    }
    if (tid == 0) {
        out[2048] = 50.f * l1 + l3;
        out[2049] = l1;
        out[2050] = l3;
    }
    for (int idx = tid; idx < 1072; idx += 256) out[2051 + idx] = slog[idx];
}

extern "C" void kernel_launch(void* const* d_in, const int* in_sizes, int n_in,
                              void* d_out, int out_size, void* d_ws, size_t ws_size,
                              hipStream_t stream) {
    const float* X        = (const float*)d_in[0];
    const float* Yt       = (const float*)d_in[1];
    const float* wpe      = (const float*)d_in[2];
    const float* ln1_g    = (const float*)d_in[3];
    const float* ln1_b    = (const float*)d_in[4];
    const float* attn_w   = (const float*)d_in[5];
    const float* attn_b   = (const float*)d_in[6];
    const float* apw      = (const float*)d_in[7];
    const float* apb      = (const float*)d_in[8];
    const float* ln2_g    = (const float*)d_in[9];
    const float* ln2_b    = (const float*)d_in[10];
    const float* fcw      = (const float*)d_in[11];
    const float* fcb      = (const float*)d_in[12];
    const float* mpw      = (const float*)d_in[13];
    const float* mpb      = (const float*)d_in[14];
    const float* lnf_g    = (const float*)d_in[15];
    const float* lnf_b    = (const float*)d_in[16];
    const float* head_w   = (const float*)d_in[17];
    const float* head_b   = (const float*)d_in[18];

    char* ws = (char*)d_ws;
    const size_t MB = 1048576;
    __bf16* xres   = (__bf16*)(ws + 0 * MB);    // 8 MB
    __bf16* hb     = (__bf16*)(ws + 8 * MB);    // 8 MB; later Y3
    __bf16* Qb     = (__bf16*)(ws + 16 * MB);   // 8 MB
    __bf16* Kb     = (__bf16*)(ws + 24 * MB);   // 8 MB
    __bf16* Vb     = (__bf16*)(ws + 32 * MB);   // 8 MB; unused except Y4
    __bf16* Vt     = (__bf16*)(ws + 40 * MB);   // 8 MB
    __bf16* Y1     = (__bf16*)(ws + 48 * MB);   // 8 MB
    __bf16* Y2     = (__bf16*)(ws + 56 * MB);   // 8 MB
    __bf16* wb     = (__bf16*)(ws + 64 * MB);   // 1 MB
    float*  embsum = (float*)(ws + 65 * MB);    // 8 KB

    __bf16* Y3 = hb;     // hb dead after gemm_qkv
    __bf16* Y4 = Vb;

    __bf16* wqkv = wb;
    __bf16* wap  = wb + 196608;
    __bf16* wfc  = wb + 262144;
    __bf16* wmp  = wb + 393216;

    embed_prep_k<<<Mrows, 256, 0, stream>>>(X, wpe, ln1_g, ln1_b,
                                            attn_w, apw, fcw, mpw, wb, embsum, xres, hb);
    gemm_qkv<<<dim3(6, 128), 256, 0, stream>>>(hb, wqkv, attn_b, Qb, Kb, (unsigned short*)Vt);
    attn6_k<<<1280, 256, 0, stream>>>(Qb, Kb, Vt, Y1, Y2, Y3, Y4);
    mega_k<<<512, 256, 0, stream>>>(Y1, Y2, Y3, Y4, wap, apb, xres, ln2_g, ln2_b,
                                    wfc, fcb, wmp, mpb, lnf_g, lnf_b, embsum);
    final_k<<<1, 256, 0, stream>>>(embsum, Yt, head_w, head_b, (float*)d_out);
}